// Round 1
// baseline (176.606 us; speedup 1.0000x reference)
//
#include <hip/hip_runtime.h>

// Fusion_loss: 3 modalities of Mahalanobis-distance softmax fusion.
// K=64 classes, Q=128 queries/class, DIM=1024. Rows M = 8192.
//
// R10: fusion_main was latency/sync-bound (MfmaUtil 2.6%, VALU 19%, HBM 17%,
// 1.57M bank-conflict cycles): 8 barriers/block around 4B-wide DMA, plus a
// 12.6MB pred round-trip + finalize1. The MFMA A-fragment pattern
// (row=l15, k=quad*8) is directly loadable from global as 2x float4/lane
// (each 128B row segment fully consumed in-iteration -> cacheline-efficient;
// the 4 col-waves re-read rows through L1/L2). So: one block = 16 rows x
// ALL 3 modalities x full K, 12 waves (wave = (m, col-quarter)), ZERO
// main-loop syncs, no staging LDS, no DMA. Softmax + fused argmax + loss
// finish in-block; only 512+512 scalars leave. finalize1 deleted.

typedef _Float16 half8 __attribute__((ext_vector_type(8)));
typedef float    floatx4 __attribute__((ext_vector_type(4)));

#define NCLS   64
#define QPC    128
#define DIM    1024
#define NROWS  (NCLS * QPC)      // 8192
#define NRT    (NROWS / 16)      // 512 row tiles

// ws layout
#define OFF_W      0                          // f16 protos, B-frag units
#define W_BYTES    (3 * NCLS * DIM * 2)       // 393216
#define OFF_P2     W_BYTES                    // 768 B
#define OFF_LP     (OFF_P2 + 3 * NCLS * 4)    // 512 floats
#define OFF_CP     (OFF_LP + NRT * 4)         // 512 floats
#define WS_NEED    (OFF_CP + NRT * 4)

// ---------------- prep: protos -> f16 B-frag layout + p2 ----------------
// Unit (m,kcg,t) = 1KB: lane (l15,quad) holds 8 halves = col t*16+l15,
// k = kcg*32 + quad*8 .. +8.  p2[m*64+c] via atomics (f32, exact protos).
__global__ __launch_bounds__(64) void prep_protos(
    const float* __restrict__ Ptf, const float* __restrict__ Pde,
    const float* __restrict__ Pff, _Float16* __restrict__ W,
    float* __restrict__ p2)
{
    const int m    = blockIdx.x >> 5;
    const int kcg  = blockIdx.x & 31;
    const int lane = threadIdx.x;
    const int l15  = lane & 15;
    const int quad = lane >> 4;
    const float* __restrict__ P = (m == 0) ? Ptf : (m == 1) ? Pde : Pff;

    #pragma unroll
    for (int t = 0; t < 4; ++t) {
        const float* src = P + (size_t)(t * 16 + l15) * DIM + kcg * 32 + quad * 8;
        const float4 b0 = *reinterpret_cast<const float4*>(src);
        const float4 b1 = *reinterpret_cast<const float4*>(src + 4);
        half8 h;
        h[0] = (_Float16)b0.x; h[1] = (_Float16)b0.y;
        h[2] = (_Float16)b0.z; h[3] = (_Float16)b0.w;
        h[4] = (_Float16)b1.x; h[5] = (_Float16)b1.y;
        h[6] = (_Float16)b1.z; h[7] = (_Float16)b1.w;
        *reinterpret_cast<half8*>(W + ((size_t)(m * 32 + kcg) * 4 + t) * 512 + lane * 8) = h;

        float s = b0.x*b0.x + b0.y*b0.y + b0.z*b0.z + b0.w*b0.w
                + b1.x*b1.x + b1.y*b1.y + b1.z*b1.z + b1.w*b1.w;
        s += __shfl_xor(s, 16);
        s += __shfl_xor(s, 32);
        if (quad == 0) atomicAdd(&p2[m * 64 + t * 16 + l15], s);
    }
}

// ---------------- main: all 3 m, full K, direct-load GEMM + in-block fuse --
// block = row-tile (16 rows); 12 waves; wave w: m = w>>2, cq = w&3.
// Wave tile: 16 rows x cols cq*16..+15 of modality m.
__global__ __launch_bounds__(768, 6) void fusion_all(
    const float* __restrict__ Xtf, const float* __restrict__ Xde,
    const float* __restrict__ Xff,
    const float* __restrict__ Vtf, const float* __restrict__ Vde,
    const float* __restrict__ Vff,
    const _Float16* __restrict__ W, const float* __restrict__ p2g,
    float* __restrict__ lossPart,  // [512]
    float* __restrict__ cntPart)   // [512]
{
    __shared__ float x2s[3][16];
    __shared__ float mxW[3][4][16];
    __shared__ float sW[3][4][16];
    __shared__ float predS[3][16][66];   // +2 pad: quad stride 264 -> bank +8
    __shared__ float lossW[12];
    __shared__ float cntW[4];

    const int tid  = threadIdx.x;
    const int w    = tid >> 6;        // 0..11
    const int lane = tid & 63;
    const int l15  = lane & 15;
    const int quad = lane >> 4;
    const int m    = w >> 2;          // modality
    const int cq   = w & 3;           // col quarter
    const int rowBase = blockIdx.x * 16;

    const float* __restrict__ X = (m == 0) ? Xtf : (m == 1) ? Xde : Xff;
    const float* __restrict__ V = (m == 0) ? Vtf : (m == 1) ? Vde : Vff;
    const float  wgt = (m == 0) ? 1.0f : (m == 1) ? 0.8f : 0.6f;

    // A-frag source: row = rowBase+l15, k = kc*32 + quad*8 .. +8
    const float* __restrict__ xr = X + (size_t)(rowBase + l15) * DIM + quad * 8;
    // B-frag source: unit (m, kc, cq); stride per kc = 4*512 halves
    const _Float16* __restrict__ wb = W + ((size_t)(m * 32) * 4 + cq) * 512 + lane * 8;

    floatx4 d = (floatx4){0.f, 0.f, 0.f, 0.f};
    float x2p = 0.0f;

    #pragma unroll 2
    for (int kc = 0; kc < 32; ++kc) {
        const float4 a0 = *reinterpret_cast<const float4*>(xr + kc * 32);
        const float4 a1 = *reinterpret_cast<const float4*>(xr + kc * 32 + 4);
        const half8 bf = *reinterpret_cast<const half8*>(wb + (size_t)kc * 2048);

        if (cq == 0)   // one wave per m computes x2 (rows shared by 4 cq-waves)
            x2p += a0.x*a0.x + a0.y*a0.y + a0.z*a0.z + a0.w*a0.w
                 + a1.x*a1.x + a1.y*a1.y + a1.z*a1.z + a1.w*a1.w;

        half8 af;
        af[0] = (_Float16)a0.x; af[1] = (_Float16)a0.y;
        af[2] = (_Float16)a0.z; af[3] = (_Float16)a0.w;
        af[4] = (_Float16)a1.x; af[5] = (_Float16)a1.y;
        af[6] = (_Float16)a1.z; af[7] = (_Float16)a1.w;

        d = __builtin_amdgcn_mfma_f32_16x16x32_f16(af, bf, d, 0, 0, 0);
    }

    if (cq == 0) {
        x2p += __shfl_xor(x2p, 16);
        x2p += __shfl_xor(x2p, 32);
        if (quad == 0) x2s[m][l15] = x2p;
    }
    __syncthreads();

    // logits: row = quad*4+r, col = cq*16+l15 (MFMA C/D layout)
    const int col = cq * 16 + l15;
    const float vc  = V[col];
    const float p2c = p2g[m * 64 + col];
    float lg[4];
    #pragma unroll
    for (int r = 0; r < 4; ++r)
        lg[r] = (2.0f * d[r] - x2s[m][quad * 4 + r] - p2c) / vc;

    // per-wave 16-col max per row -> LDS
    #pragma unroll
    for (int r = 0; r < 4; ++r) {
        float mx = lg[r];
        #pragma unroll
        for (int dl = 1; dl <= 8; dl <<= 1) mx = fmaxf(mx, __shfl_xor(mx, dl));
        if (l15 == 0) mxW[m][cq][quad * 4 + r] = mx;
    }
    __syncthreads();

    // 64-col max, per-wave exp-sum -> LDS
    float gmx[4];
    #pragma unroll
    for (int r = 0; r < 4; ++r) {
        const int row = quad * 4 + r;
        gmx[r] = fmaxf(fmaxf(mxW[m][0][row], mxW[m][1][row]),
                       fmaxf(mxW[m][2][row], mxW[m][3][row]));
        float s = expf(lg[r] - gmx[r]);
        #pragma unroll
        for (int dl = 1; dl <= 8; dl <<= 1) s += __shfl_xor(s, dl);
        if (l15 == 0) sW[m][cq][quad * 4 + r] = s;
    }
    __syncthreads();

    // lse; loss at target col; weighted softmax -> LDS (fused across m later)
    const int y = rowBase >> 7;   // uniform across the block's 16 rows
    float lossAcc = 0.0f;
    #pragma unroll
    for (int r = 0; r < 4; ++r) {
        const int row = quad * 4 + r;
        const float lse = gmx[r] + logf(sW[m][0][row] + sW[m][1][row]
                                      + sW[m][2][row] + sW[m][3][row]);
        if (col == y) lossAcc += wgt * (lse - lg[r]);
        predS[m][row][col] = wgt * expf(lg[r] - lse);
    }
    #pragma unroll
    for (int dl = 1; dl <= 32; dl <<= 1) lossAcc += __shfl_xor(lossAcc, dl);
    if (lane == 0) lossW[w] = lossAcc;
    __syncthreads();

    // fused argmax over sum_m predS: waves 0..3, 4 rows each
    if (w < 4) {
        float cnt = 0.0f;
        #pragma unroll
        for (int r4 = 0; r4 < 4; ++r4) {
            const int row = w * 4 + r4;
            float bv = predS[0][row][lane] + predS[1][row][lane]
                     + predS[2][row][lane];
            int bc = lane;
            #pragma unroll
            for (int dl = 1; dl <= 32; dl <<= 1) {
                const float ov = __shfl_xor(bv, dl);
                const int   oc = __shfl_xor(bc, dl);
                if (ov > bv || (ov == bv && oc < bc)) { bv = ov; bc = oc; }
            }
            if (bc == y) cnt += 1.0f;   // bc uniform across lanes after butterfly
        }
        if (lane == 0) cntW[w] = cnt;
    }
    __syncthreads();

    if (tid == 0) {
        float L = 0.0f;
        #pragma unroll
        for (int i = 0; i < 12; ++i) L += lossW[i];
        lossPart[blockIdx.x] = L;
        cntPart[blockIdx.x]  = cntW[0] + cntW[1] + cntW[2] + cntW[3];
    }
}

// ---------------- finalize: scalar reduce ----------------
__global__ __launch_bounds__(256) void finalize2(
    const float* __restrict__ lossPart, const float* __restrict__ cntPart,
    float* __restrict__ out)
{
    const int tid  = threadIdx.x;
    const int lane = tid & 63;
    const int v    = tid >> 6;
    float l = 0.0f, c = 0.0f;
    for (int i = tid; i < NRT; i += 256) l += lossPart[i];
    for (int i = tid; i < NRT; i += 256) c += cntPart[i];
    #pragma unroll
    for (int dl = 1; dl <= 32; dl <<= 1) {
        l += __shfl_xor(l, dl);
        c += __shfl_xor(c, dl);
    }
    __shared__ float sl[4], sc[4];
    if (lane == 0) { sl[v] = l; sc[v] = c; }
    __syncthreads();
    if (tid == 0) {
        out[0] = (sl[0] + sl[1] + sl[2] + sl[3]) * (1.0f / NROWS);
        out[1] = (sc[0] + sc[1] + sc[2] + sc[3]) * (1.0f / NROWS);
    }
}

// ---------------- fallback (R2 kernel, used only if ws too small) --------
#define NWAVES 12
#define KSPLIT 4
#define KSLICE (DIM / KSPLIT)
#define NITER  (KSLICE / 32)
#define DSTRIDE 17
#define PSTRIDE 65

__global__ __launch_bounds__(NWAVES * 64) void fusion_loss_fallback(
    const float* __restrict__ Xtf, const float* __restrict__ Ptf, const float* __restrict__ Vtf,
    const float* __restrict__ Xde, const float* __restrict__ Pde, const float* __restrict__ Vde,
    const float* __restrict__ Xff, const float* __restrict__ Pff, const float* __restrict__ Vff,
    float* __restrict__ out)
{
    __shared__ float dpart[NWAVES][64 * DSTRIDE];
    __shared__ float x2part[NWAVES][16];
    __shared__ float p2part[NWAVES][64];
    __shared__ float predL[16 * PSTRIDE];
    __shared__ float lossL;

    const int tid  = threadIdx.x;
    const int wave = tid >> 6;
    const int lane = tid & 63;
    const int l15  = lane & 15;
    const int quad = lane >> 4;
    const int m    = wave >> 2;
    const int kq   = wave & 3;
    const int rowBase = blockIdx.x * 16;

    for (int i = tid; i < 16 * PSTRIDE; i += NWAVES * 64) predL[i] = 0.0f;
    if (tid == 0) lossL = 0.0f;

    const float* __restrict__ X = (m == 0) ? Xtf : (m == 1) ? Xde : Xff;
    const float* __restrict__ P = (m == 0) ? Ptf : (m == 1) ? Pde : Pff;
    const float* __restrict__ V = (m == 0) ? Vtf : (m == 1) ? Vde : Vff;
    const float  w = (m == 0) ? 1.0f : (m == 1) ? 0.8f : 0.6f;

    floatx4 d[4];
    #pragma unroll
    for (int t = 0; t < 4; ++t) d[t] = (floatx4){0.f, 0.f, 0.f, 0.f};
    float x2p    = 0.0f;
    float p2p[4] = {0.f, 0.f, 0.f, 0.f};

    const float* xrow = X + (size_t)(rowBase + l15) * DIM + kq * KSLICE + quad * 8;
    const float* prow[4];
    #pragma unroll
    for (int t = 0; t < 4; ++t)
        prow[t] = P + (size_t)(t * 16 + l15) * DIM + kq * KSLICE + quad * 8;

    #pragma unroll 2
    for (int kc = 0; kc < NITER; ++kc) {
        const int ko = kc * 32;
        const float4 a0 = *reinterpret_cast<const float4*>(xrow + ko);
        const float4 a1 = *reinterpret_cast<const float4*>(xrow + ko + 4);
        float4 b0[4], b1[4];
        #pragma unroll
        for (int t = 0; t < 4; ++t) {
            b0[t] = *reinterpret_cast<const float4*>(prow[t] + ko);
            b1[t] = *reinterpret_cast<const float4*>(prow[t] + ko + 4);
        }
        x2p += a0.x*a0.x + a0.y*a0.y + a0.z*a0.z + a0.w*a0.w
             + a1.x*a1.x + a1.y*a1.y + a1.z*a1.z + a1.w*a1.w;
        half8 af;
        af[0] = (_Float16)a0.x; af[1] = (_Float16)a0.y;
        af[2] = (_Float16)a0.z; af[3] = (_Float16)a0.w;
        af[4] = (_Float16)a1.x; af[5] = (_Float16)a1.y;
        af[6] = (_Float16)a1.z; af[7] = (_Float16)a1.w;
        #pragma unroll
        for (int t = 0; t < 4; ++t) {
            p2p[t] += b0[t].x*b0[t].x + b0[t].y*b0[t].y + b0[t].z*b0[t].z + b0[t].w*b0[t].w
                    + b1[t].x*b1[t].x + b1[t].y*b1[t].y + b1[t].z*b1[t].z + b1[t].w*b1[t].w;
            half8 bf;
            bf[0] = (_Float16)b0[t].x; bf[1] = (_Float16)b0[t].y;
            bf[2] = (_Float16)b0[t].z; bf[3] = (_Float16)b0[t].w;
            bf[4] = (_Float16)b1[t].x; bf[5] = (_Float16)b1[t].y;
            bf[6] = (_Float16)b1[t].z; bf[7] = (_Float16)b1[t].w;
            d[t] = __builtin_amdgcn_mfma_f32_16x16x32_f16(af, bf, d[t], 0, 0, 0);
        }
    }

    x2p += __shfl_xor(x2p, 16);
    x2p += __shfl_xor(x2p, 32);
    #pragma unroll
    for (int t = 0; t < 4; ++t) {
        p2p[t] += __shfl_xor(p2p[t], 16);
        p2p[t] += __shfl_xor(p2p[t], 32);
    }
    {
        float* dp = &dpart[wave][lane * DSTRIDE];
        #pragma unroll
        for (int t = 0; t < 4; ++t)
            *reinterpret_cast<float4*>(dp + t * 4) =
                make_float4(d[t][0], d[t][1], d[t][2], d[t][3]);
        if (quad == 0) {
            x2part[wave][l15] = x2p;
            #pragma unroll
            for (int t = 0; t < 4; ++t) p2part[wave][t * 16 + l15] = p2p[t];
        }
    }
    __syncthreads();

    const int y = rowBase >> 7;

    if (kq == 0) {
        floatx4 dsum[4];
        #pragma unroll
        for (int t = 0; t < 4; ++t) dsum[t] = (floatx4){0.f, 0.f, 0.f, 0.f};
        float x2r[4] = {0.f, 0.f, 0.f, 0.f};
        float p2c[4] = {0.f, 0.f, 0.f, 0.f};
        #pragma unroll
        for (int k2 = 0; k2 < KSPLIT; ++k2) {
            const int wv = m * 4 + k2;
            const float* src = &dpart[wv][lane * DSTRIDE];
            #pragma unroll
            for (int t = 0; t < 4; ++t) {
                const float4 vv = *reinterpret_cast<const float4*>(src + t * 4);
                dsum[t][0] += vv.x; dsum[t][1] += vv.y; dsum[t][2] += vv.z; dsum[t][3] += vv.w;
            }
            #pragma unroll
            for (int r = 0; r < 4; ++r) x2r[r] += x2part[wv][quad * 4 + r];
            #pragma unroll
            for (int t = 0; t < 4; ++t) p2c[t] += p2part[wv][t * 16 + l15];
        }
        float vc[4];
        #pragma unroll
        for (int t = 0; t < 4; ++t) vc[t] = V[t * 16 + l15];

        float lossAcc = 0.0f;
        #pragma unroll
        for (int r = 0; r < 4; ++r) {
            float lg[4];
            #pragma unroll
            for (int t = 0; t < 4; ++t)
                lg[t] = (2.0f * dsum[t][r] - x2r[r] - p2c[t]) / vc[t];
            float mx = fmaxf(fmaxf(lg[0], lg[1]), fmaxf(lg[2], lg[3]));
            #pragma unroll
            for (int dl = 1; dl <= 8; dl <<= 1) mx = fmaxf(mx, __shfl_xor(mx, dl));
            float s = expf(lg[0] - mx) + expf(lg[1] - mx)
                    + expf(lg[2] - mx) + expf(lg[3] - mx);
            #pragma unroll
            for (int dl = 1; dl <= 8; dl <<= 1) s += __shfl_xor(s, dl);
            const float lse = mx + logf(s);
            const int row = quad * 4 + r;
            #pragma unroll
            for (int t = 0; t < 4; ++t) {
                const int colc = t * 16 + l15;
                if (colc == y) lossAcc += w * (lse - lg[t]);
                atomicAdd(&predL[row * PSTRIDE + colc], w * expf(lg[t] - lse));
            }
        }
        #pragma unroll
        for (int dl = 1; dl <= 32; dl <<= 1) lossAcc += __shfl_xor(lossAcc, dl);
        if (lane == 0) atomicAdd(&lossL, lossAcc);
    }
    __syncthreads();

    if (wave == 0) {
        float cnt = 0.0f;
        #pragma unroll 1
        for (int r = 0; r < 16; ++r) {
            float bv = predL[r * PSTRIDE + lane];
            int   bc = lane;
            #pragma unroll
            for (int dl = 1; dl <= 32; dl <<= 1) {
                const float ov = __shfl_xor(bv, dl);
                const int   oc = __shfl_xor(bc, dl);
                if (ov > bv || (ov == bv && oc < bc)) { bv = ov; bc = oc; }
            }
            if (lane == 0 && bc == y) cnt += 1.0f;
        }
        if (lane == 0) {
            atomicAdd(&out[0], lossL * (1.0f / NROWS));
            atomicAdd(&out[1], cnt * (1.0f / NROWS));
        }
    }
}

extern "C" void kernel_launch(void* const* d_in, const int* in_sizes, int n_in,
                              void* d_out, int out_size, void* d_ws, size_t ws_size,
                              hipStream_t stream) {
    const float* Xtf = (const float*)d_in[0];
    const float* Ptf = (const float*)d_in[1];
    const float* Vtf = (const float*)d_in[2];
    const float* Xde = (const float*)d_in[3];
    const float* Pde = (const float*)d_in[4];
    const float* Vde = (const float*)d_in[5];
    const float* Xff = (const float*)d_in[6];
    const float* Pff = (const float*)d_in[7];
    const float* Vff = (const float*)d_in[8];
    float* out = (float*)d_out;

    if (ws_size >= (size_t)WS_NEED) {
        char* ws = (char*)d_ws;
        _Float16* W     = (_Float16*)(ws + OFF_W);
        float*    p2    = (float*)(ws + OFF_P2);
        float*    lossP = (float*)(ws + OFF_LP);
        float*    cntP  = (float*)(ws + OFF_CP);

        hipMemsetAsync(p2, 0, 3 * NCLS * sizeof(float), stream);
        prep_protos<<<dim3(96), dim3(64), 0, stream>>>(Ptf, Pde, Pff, W, p2);
        fusion_all<<<dim3(NRT), dim3(768), 0, stream>>>(
            Xtf, Xde, Xff, Vtf, Vde, Vff, W, p2, lossP, cntP);
        finalize2<<<dim3(1), dim3(256), 0, stream>>>(lossP, cntP, out);
    } else {
        hipMemsetAsync(out, 0, 2 * sizeof(float), stream);
        fusion_loss_fallback<<<dim3(NROWS / 16), dim3(NWAVES * 64), 0, stream>>>(
            Xtf, Ptf, Vtf, Xde, Pde, Vde, Xff, Pff, Vff, out);
    }
}

// Round 4
// 146.845 us; speedup vs baseline: 1.2027x; 1.2027x over previous
//
#include <hip/hip_runtime.h>

// Fusion_loss: 3 modalities of Mahalanobis-distance softmax fusion.
// K=64 classes, Q=128 queries/class, DIM=1024. Rows M = 8192.
//
// R13: R11/R12 (counted-vmcnt + raw s_barrier) likely hung the GPU twice.
// This round removes ALL inline-asm sync (m152 lesson: untested barrier
// structures race/hang) and uses the compiler-safe minimum-2-phase
// pipeline: double-buffered LDS, width-16 global_load_lds, stage(c+1)
// issued at TOP of iter (compile-time fence only), compute(c) overlaps
// the in-flight DMA, ONE __syncthreads per chunk (its implicit vmcnt(0)
// drain lands after compute already covered the DMA window; 2 blocks/CU
// overlap each other's drains). Keeps R10's fused all-3-m epilogue (no
// pred round-trip) and the XOR bank-conflict swizzle.
// 512 blocks x 768 thr, 63.6KB LDS -> 2 blocks/CU, 24 waves/CU.

typedef _Float16 half8 __attribute__((ext_vector_type(8)));
typedef float    floatx4 __attribute__((ext_vector_type(4)));

#define NCLS   64
#define QPC    128
#define DIM    1024
#define NROWS  (NCLS * QPC)      // 8192
#define NRT    (NROWS / 16)      // 512 row tiles

// ws layout
#define OFF_W      0                          // f16 protos, B-frag units
#define W_BYTES    (3 * NCLS * DIM * 2)       // 393216
#define OFF_P2     W_BYTES                    // 768 B
#define OFF_LP     (OFF_P2 + 3 * NCLS * 4)    // 512 floats
#define OFF_CP     (OFF_LP + NRT * 4)         // 512 floats
#define WS_NEED    (OFF_CP + NRT * 4)

__device__ __forceinline__ void dma16(const float* g, float* l) {
    __builtin_amdgcn_global_load_lds(
        (const __attribute__((address_space(1))) void*)g,
        (__attribute__((address_space(3))) void*)l,
        16, 0, 0);
}

// ---------------- prep: protos -> f16 B-frag layout + p2 ----------------
// Unit (m,kcg,t) = 1KB: lane (l15,quad) holds 8 halves = col t*16+l15,
// k = kcg*32 + quad*8 .. +8.  p2[m*64+c] via atomics (f32, exact protos).
__global__ __launch_bounds__(64) void prep_protos(
    const float* __restrict__ Ptf, const float* __restrict__ Pde,
    const float* __restrict__ Pff, _Float16* __restrict__ W,
    float* __restrict__ p2)
{
    const int m    = blockIdx.x >> 5;
    const int kcg  = blockIdx.x & 31;
    const int lane = threadIdx.x;
    const int l15  = lane & 15;
    const int quad = lane >> 4;
    const float* __restrict__ P = (m == 0) ? Ptf : (m == 1) ? Pde : Pff;

    #pragma unroll
    for (int t = 0; t < 4; ++t) {
        const float* src = P + (size_t)(t * 16 + l15) * DIM + kcg * 32 + quad * 8;
        const float4 b0 = *reinterpret_cast<const float4*>(src);
        const float4 b1 = *reinterpret_cast<const float4*>(src + 4);
        half8 h;
        h[0] = (_Float16)b0.x; h[1] = (_Float16)b0.y;
        h[2] = (_Float16)b0.z; h[3] = (_Float16)b0.w;
        h[4] = (_Float16)b1.x; h[5] = (_Float16)b1.y;
        h[6] = (_Float16)b1.z; h[7] = (_Float16)b1.w;
        *reinterpret_cast<half8*>(W + ((size_t)(m * 32 + kcg) * 4 + t) * 512 + lane * 8) = h;

        float s = b0.x*b0.x + b0.y*b0.y + b0.z*b0.z + b0.w*b0.w
                + b1.x*b1.x + b1.y*b1.y + b1.z*b1.z + b1.w*b1.w;
        s += __shfl_xor(s, 16);
        s += __shfl_xor(s, 32);
        if (quad == 0) atomicAdd(&p2[m * 64 + t * 16 + l15], s);
    }
}

// ---------------- main: all 3 m, LDS-staged pipelined GEMM + in-block fuse --
// block = row-tile (16 rows); 12 waves; wave w: m = w>>2, cq = w&3.
// Wave tile: 16 rows x cols cq*16..+15 of modality m.
// LDS A-tile layout: buf[b][m][row][128 words], word p of row r holds
// X[r, p ^ ((r&7)*4)]  (XOR swizzle; involution; float4 blocks preserved
// since the XOR operand is a multiple of 4 words).
__global__ __launch_bounds__(768, 6) void fusion_all(
    const float* __restrict__ Xtf, const float* __restrict__ Xde,
    const float* __restrict__ Xff,
    const float* __restrict__ Vtf, const float* __restrict__ Vde,
    const float* __restrict__ Vff,
    const _Float16* __restrict__ W, const float* __restrict__ p2g,
    float* __restrict__ lossPart,  // [512]
    float* __restrict__ cntPart)   // [512]
{
    __shared__ float buf[2][3][16][128];   // 49152 B, DMA-only writes
    __shared__ float x2s[3][16];
    __shared__ float mxW[3][4][16];
    __shared__ float sW[3][4][16];
    __shared__ float predS[3][16][66];     // +2 pad
    __shared__ float lossW[12];
    __shared__ float cntW[4];

    const int tid  = threadIdx.x;
    const int w    = tid >> 6;        // 0..11
    const int lane = tid & 63;
    const int l15  = lane & 15;
    const int quad = lane >> 4;
    const int m    = w >> 2;          // modality
    const int cq   = w & 3;           // col quarter
    const int rowBase = blockIdx.x * 16;

    const float* __restrict__ X = (m == 0) ? Xtf : (m == 1) ? Xde : Xff;
    const float* __restrict__ V = (m == 0) ? Vtf : (m == 1) ? Vde : Vff;
    const float  wgt = (m == 0) ? 1.0f : (m == 1) ? 0.8f : 0.6f;

    // Staging: wave (m,cq) stages rows cq*4..+4 of modality m.
    // Each dma16 covers 2 rows (64 lanes x 16B = 1KB): lane l -> LDS words
    // (l&31)*4 of local row base + (l>>5); source col pre-swizzled.
    const int rl0 = cq * 4 + (lane >> 5);       // call-0 row
    const int rl1 = rl0 + 2;                    // call-1 row
    const int sc0 = ((lane & 31) * 4) ^ ((rl0 & 7) * 4);
    const int sc1 = ((lane & 31) * 4) ^ ((rl1 & 7) * 4);
    const float* __restrict__ s0 = X + (size_t)(rowBase + rl0) * DIM + sc0;
    const float* __restrict__ s1 = X + (size_t)(rowBase + rl1) * DIM + sc1;

    // B-frag source: unit (m, kcg, cq); stride per kcg = 4*512 halves
    const _Float16* __restrict__ wb = W + ((size_t)(m * 32) * 4 + cq) * 512 + lane * 8;

    floatx4 d = (floatx4){0.f, 0.f, 0.f, 0.f};
    float x2p = 0.0f;

    const int sw     = (l15 & 7) << 2;   // read-side XOR (words)
    const int rowOff = l15 * 128;

    // prologue: stage chunk 0 into buf[0]; barrier drains it (vmcnt(0)
    // implicit in __syncthreads).
    dma16(s0, &buf[0][m][cq * 4][0]);
    dma16(s1, &buf[0][m][cq * 4 + 2][0]);
    __syncthreads();

    #pragma unroll
    for (int c = 0; c < 8; ++c) {
        // Issue chunk c+1 DMA FIRST so it streams under compute(c).
        // Target buffer's iter-(c-1) readers were drained by the previous
        // __syncthreads (lgkmcnt(0)), so the overwrite is safe.
        if (c < 7) {
            dma16(s0 + (c + 1) * 128, &buf[(c + 1) & 1][m][cq * 4][0]);
            dma16(s1 + (c + 1) * 128, &buf[(c + 1) & 1][m][cq * 4 + 2][0]);
        }
        asm volatile("" ::: "memory");  // compile-time only: pin DMA above compute

        const float* tb = &buf[c & 1][m][0][0];
        #pragma unroll
        for (int kc = 0; kc < 4; ++kc) {
            const float4 a0 = *reinterpret_cast<const float4*>(
                tb + rowOff + kc * 32 + ((quad * 8) ^ sw));
            const float4 a1 = *reinterpret_cast<const float4*>(
                tb + rowOff + kc * 32 + (((quad * 8) + 4) ^ sw));
            const half8 bf = *reinterpret_cast<const half8*>(
                wb + (size_t)(c * 4 + kc) * 2048);

            if (cq == 0)   // one wave per m computes x2 (rows shared by 4 cq)
                x2p += a0.x*a0.x + a0.y*a0.y + a0.z*a0.z + a0.w*a0.w
                     + a1.x*a1.x + a1.y*a1.y + a1.z*a1.z + a1.w*a1.w;

            half8 af;
            af[0] = (_Float16)a0.x; af[1] = (_Float16)a0.y;
            af[2] = (_Float16)a0.z; af[3] = (_Float16)a0.w;
            af[4] = (_Float16)a1.x; af[5] = (_Float16)a1.y;
            af[6] = (_Float16)a1.z; af[7] = (_Float16)a1.w;

            d = __builtin_amdgcn_mfma_f32_16x16x32_f16(af, bf, d, 0, 0, 0);
        }
        // One barrier per chunk: drains this iter's ds_reads (lgkm) and the
        // chunk c+1 DMA (vmcnt) -> buf[(c+1)&1] resident for next iter.
        __syncthreads();
    }

    if (cq == 0) {
        x2p += __shfl_xor(x2p, 16);
        x2p += __shfl_xor(x2p, 32);
        if (quad == 0) x2s[m][l15] = x2p;
    }
    __syncthreads();

    // logits: row = quad*4+r, col = cq*16+l15 (MFMA C/D layout)
    const int col = cq * 16 + l15;
    const float vc  = V[col];
    const float p2c = p2g[m * 64 + col];
    float lg[4];
    #pragma unroll
    for (int r = 0; r < 4; ++r)
        lg[r] = (2.0f * d[r] - x2s[m][quad * 4 + r] - p2c) / vc;

    // per-wave 16-col max per row -> LDS
    #pragma unroll
    for (int r = 0; r < 4; ++r) {
        float mx = lg[r];
        #pragma unroll
        for (int dl = 1; dl <= 8; dl <<= 1) mx = fmaxf(mx, __shfl_xor(mx, dl));
        if (l15 == 0) mxW[m][cq][quad * 4 + r] = mx;
    }
    __syncthreads();

    // 64-col max, per-wave exp-sum -> LDS
    float gmx[4];
    #pragma unroll
    for (int r = 0; r < 4; ++r) {
        const int row = quad * 4 + r;
        gmx[r] = fmaxf(fmaxf(mxW[m][0][row], mxW[m][1][row]),
                       fmaxf(mxW[m][2][row], mxW[m][3][row]));
        float s = expf(lg[r] - gmx[r]);
        #pragma unroll
        for (int dl = 1; dl <= 8; dl <<= 1) s += __shfl_xor(s, dl);
        if (l15 == 0) sW[m][cq][quad * 4 + r] = s;
    }
    __syncthreads();

    // lse; loss at target col; weighted softmax -> LDS
    const int y = rowBase >> 7;   // uniform across the block's 16 rows
    float lossAcc = 0.0f;
    #pragma unroll
    for (int r = 0; r < 4; ++r) {
        const int row = quad * 4 + r;
        const float lse = gmx[r] + logf(sW[m][0][row] + sW[m][1][row]
                                      + sW[m][2][row] + sW[m][3][row]);
        if (col == y) lossAcc += wgt * (lse - lg[r]);
        predS[m][row][col] = wgt * expf(lg[r] - lse);
    }
    #pragma unroll
    for (int dl = 1; dl <= 32; dl <<= 1) lossAcc += __shfl_xor(lossAcc, dl);
    if (lane == 0) lossW[w] = lossAcc;
    __syncthreads();

    // fused argmax over sum_m predS: waves 0..3, 4 rows each
    if (w < 4) {
        float cnt = 0.0f;
        #pragma unroll
        for (int r4 = 0; r4 < 4; ++r4) {
            const int row = w * 4 + r4;
            float bv = predS[0][row][lane] + predS[1][row][lane]
                     + predS[2][row][lane];
            int bc = lane;
            #pragma unroll
            for (int dl = 1; dl <= 32; dl <<= 1) {
                const float ov = __shfl_xor(bv, dl);
                const int   oc = __shfl_xor(bc, dl);
                if (ov > bv || (ov == bv && oc < bc)) { bv = ov; bc = oc; }
            }
            if (bc == y) cnt += 1.0f;
        }
        if (lane == 0) cntW[w] = cnt;
    }
    __syncthreads();

    if (tid == 0) {
        float L = 0.0f;
        #pragma unroll
        for (int i = 0; i < 12; ++i) L += lossW[i];
        lossPart[blockIdx.x] = L;
        cntPart[blockIdx.x]  = cntW[0] + cntW[1] + cntW[2] + cntW[3];
    }
}

// ---------------- finalize: scalar reduce ----------------
__global__ __launch_bounds__(256) void finalize2(
    const float* __restrict__ lossPart, const float* __restrict__ cntPart,
    float* __restrict__ out)
{
    const int tid  = threadIdx.x;
    const int lane = tid & 63;
    const int v    = tid >> 6;
    float l = 0.0f, c = 0.0f;
    for (int i = tid; i < NRT; i += 256) l += lossPart[i];
    for (int i = tid; i < NRT; i += 256) c += cntPart[i];
    #pragma unroll
    for (int dl = 1; dl <= 32; dl <<= 1) {
        l += __shfl_xor(l, dl);
        c += __shfl_xor(c, dl);
    }
    __shared__ float sl[4], sc[4];
    if (lane == 0) { sl[v] = l; sc[v] = c; }
    __syncthreads();
    if (tid == 0) {
        out[0] = (sl[0] + sl[1] + sl[2] + sl[3]) * (1.0f / NROWS);
        out[1] = (sc[0] + sc[1] + sc[2] + sc[3]) * (1.0f / NROWS);
    }
}

// ---------------- fallback (R2 kernel, used only if ws too small) --------
#define NWAVES 12
#define KSPLIT 4
#define KSLICE (DIM / KSPLIT)
#define NITER  (KSLICE / 32)
#define DSTRIDE 17
#define PSTRIDE 65

__global__ __launch_bounds__(NWAVES * 64) void fusion_loss_fallback(
    const float* __restrict__ Xtf, const float* __restrict__ Ptf, const float* __restrict__ Vtf,
    const float* __restrict__ Xde, const float* __restrict__ Pde, const float* __restrict__ Vde,
    const float* __restrict__ Xff, const float* __restrict__ Pff, const float* __restrict__ Vff,
    float* __restrict__ out)
{
    __shared__ float dpart[NWAVES][64 * DSTRIDE];
    __shared__ float x2part[NWAVES][16];
    __shared__ float p2part[NWAVES][64];
    __shared__ float predL[16 * PSTRIDE];
    __shared__ float lossL;

    const int tid  = threadIdx.x;
    const int wave = tid >> 6;
    const int lane = tid & 63;
    const int l15  = lane & 15;
    const int quad = lane >> 4;
    const int m    = wave >> 2;
    const int kq   = wave & 3;
    const int rowBase = blockIdx.x * 16;

    for (int i = tid; i < 16 * PSTRIDE; i += NWAVES * 64) predL[i] = 0.0f;
    if (tid == 0) lossL = 0.0f;

    const float* __restrict__ X = (m == 0) ? Xtf : (m == 1) ? Xde : Xff;
    const float* __restrict__ P = (m == 0) ? Ptf : (m == 1) ? Pde : Pff;
    const float* __restrict__ V = (m == 0) ? Vtf : (m == 1) ? Vde : Vff;
    const float  w = (m == 0) ? 1.0f : (m == 1) ? 0.8f : 0.6f;

    floatx4 d[4];
    #pragma unroll
    for (int t = 0; t < 4; ++t) d[t] = (floatx4){0.f, 0.f, 0.f, 0.f};
    float x2p    = 0.0f;
    float p2p[4] = {0.f, 0.f, 0.f, 0.f};

    const float* xrow = X + (size_t)(rowBase + l15) * DIM + kq * KSLICE + quad * 8;
    const float* prow[4];
    #pragma unroll
    for (int t = 0; t < 4; ++t)
        prow[t] = P + (size_t)(t * 16 + l15) * DIM + kq * KSLICE + quad * 8;

    #pragma unroll 2
    for (int kc = 0; kc < NITER; ++kc) {
        const int ko = kc * 32;
        const float4 a0 = *reinterpret_cast<const float4*>(xrow + ko);
        const float4 a1 = *reinterpret_cast<const float4*>(xrow + ko + 4);
        float4 b0[4], b1[4];
        #pragma unroll
        for (int t = 0; t < 4; ++t) {
            b0[t] = *reinterpret_cast<const float4*>(prow[t] + ko);
            b1[t] = *reinterpret_cast<const float4*>(prow[t] + ko + 4);
        }
        x2p += a0.x*a0.x + a0.y*a0.y + a0.z*a0.z + a0.w*a0.w
             + a1.x*a1.x + a1.y*a1.y + a1.z*a1.z + a1.w*a1.w;
        half8 af;
        af[0] = (_Float16)a0.x; af[1] = (_Float16)a0.y;
        af[2] = (_Float16)a0.z; af[3] = (_Float16)a0.w;
        af[4] = (_Float16)a1.x; af[5] = (_Float16)a1.y;
        af[6] = (_Float16)a1.z; af[7] = (_Float16)a1.w;
        #pragma unroll
        for (int t = 0; t < 4; ++t) {
            p2p[t] += b0[t].x*b0[t].x + b0[t].y*b0[t].y + b0[t].z*b0[t].z + b0[t].w*b0[t].w
                    + b1[t].x*b1[t].x + b1[t].y*b1[t].y + b1[t].z*b1[t].z + b1[t].w*b1[t].w;
            half8 bf;
            bf[0] = (_Float16)b0[t].x; bf[1] = (_Float16)b0[t].y;
            bf[2] = (_Float16)b0[t].z; bf[3] = (_Float16)b0[t].w;
            bf[4] = (_Float16)b1[t].x; bf[5] = (_Float16)b1[t].y;
            bf[6] = (_Float16)b1[t].z; bf[7] = (_Float16)b1[t].w;
            d[t] = __builtin_amdgcn_mfma_f32_16x16x32_f16(af, bf, d[t], 0, 0, 0);
        }
    }

    x2p += __shfl_xor(x2p, 16);
    x2p += __shfl_xor(x2p, 32);
    #pragma unroll
    for (int t = 0; t < 4; ++t) {
        p2p[t] += __shfl_xor(p2p[t], 16);
        p2p[t] += __shfl_xor(p2p[t], 32);
    }
    {
        float* dp = &dpart[wave][lane * DSTRIDE];
        #pragma unroll
        for (int t = 0; t < 4; ++t)
            *reinterpret_cast<float4*>(dp + t * 4) =
                make_float4(d[t][0], d[t][1], d[t][2], d[t][3]);
        if (quad == 0) {
            x2part[wave][l15] = x2p;
            #pragma unroll
            for (int t = 0; t < 4; ++t) p2part[wave][t * 16 + l15] = p2p[t];
        }
    }
    __syncthreads();

    const int y = rowBase >> 7;

    if (kq == 0) {
        floatx4 dsum[4];
        #pragma unroll
        for (int t = 0; t < 4; ++t) dsum[t] = (floatx4){0.f, 0.f, 0.f, 0.f};
        float x2r[4] = {0.f, 0.f, 0.f, 0.f};
        float p2c[4] = {0.f, 0.f, 0.f, 0.f};
        #pragma unroll
        for (int k2 = 0; k2 < KSPLIT; ++k2) {
            const int wv = m * 4 + k2;
            const float* src = &dpart[wv][lane * DSTRIDE];
            #pragma unroll
            for (int t = 0; t < 4; ++t) {
                const float4 vv = *reinterpret_cast<const float4*>(src + t * 4);
                dsum[t][0] += vv.x; dsum[t][1] += vv.y; dsum[t][2] += vv.z; dsum[t][3] += vv.w;
            }
            #pragma unroll
            for (int r = 0; r < 4; ++r) x2r[r] += x2part[wv][quad * 4 + r];
            #pragma unroll
            for (int t = 0; t < 4; ++t) p2c[t] += p2part[wv][t * 16 + l15];
        }
        float vc[4];
        #pragma unroll
        for (int t = 0; t < 4; ++t) vc[t] = V[t * 16 + l15];

        float lossAcc = 0.0f;
        #pragma unroll
        for (int r = 0; r < 4; ++r) {
            float lg[4];
            #pragma unroll
            for (int t = 0; t < 4; ++t)
                lg[t] = (2.0f * dsum[t][r] - x2r[r] - p2c[t]) / vc[t];
            float mx = fmaxf(fmaxf(lg[0], lg[1]), fmaxf(lg[2], lg[3]));
            #pragma unroll
            for (int dl = 1; dl <= 8; dl <<= 1) mx = fmaxf(mx, __shfl_xor(mx, dl));
            float s = expf(lg[0] - mx) + expf(lg[1] - mx)
                    + expf(lg[2] - mx) + expf(lg[3] - mx);
            #pragma unroll
            for (int dl = 1; dl <= 8; dl <<= 1) s += __shfl_xor(s, dl);
            const float lse = mx + logf(s);
            const int row = quad * 4 + r;
            #pragma unroll
            for (int t = 0; t < 4; ++t) {
                const int colc = t * 16 + l15;
                if (colc == y) lossAcc += w * (lse - lg[t]);
                atomicAdd(&predL[row * PSTRIDE + colc], w * expf(lg[t] - lse));
            }
        }
        #pragma unroll
        for (int dl = 1; dl <= 32; dl <<= 1) lossAcc += __shfl_xor(lossAcc, dl);
        if (lane == 0) atomicAdd(&lossL, lossAcc);
    }
    __syncthreads();

    if (wave == 0) {
        float cnt = 0.0f;
        #pragma unroll 1
        for (int r = 0; r < 16; ++r) {
            float bv = predL[r * PSTRIDE + lane];
            int   bc = lane;
            #pragma unroll
            for (int dl = 1; dl <= 32; dl <<= 1) {
                const float ov = __shfl_xor(bv, dl);
                const int   oc = __shfl_xor(bc, dl);
                if (ov > bv || (ov == bv && oc < bc)) { bv = ov; bc = oc; }
            }
            if (lane == 0 && bc == y) cnt += 1.0f;
        }
        if (lane == 0) {
            atomicAdd(&out[0], lossL * (1.0f / NROWS));
            atomicAdd(&out[1], cnt * (1.0f / NROWS));
        }
    }
}

extern "C" void kernel_launch(void* const* d_in, const int* in_sizes, int n_in,
                              void* d_out, int out_size, void* d_ws, size_t ws_size,
                              hipStream_t stream) {
    const float* Xtf = (const float*)d_in[0];
    const float* Ptf = (const float*)d_in[1];
    const float* Vtf = (const float*)d_in[2];
    const float* Xde = (const float*)d_in[3];
    const float* Pde = (const float*)d_in[4];
    const float* Vde = (const float*)d_in[5];
    const float* Xff = (const float*)d_in[6];
    const float* Pff = (const float*)d_in[7];
    const float* Vff = (const float*)d_in[8];
    float* out = (float*)d_out;

    if (ws_size >= (size_t)WS_NEED) {
        char* ws = (char*)d_ws;
        _Float16* W     = (_Float16*)(ws + OFF_W);
        float*    p2    = (float*)(ws + OFF_P2);
        float*    lossP = (float*)(ws + OFF_LP);
        float*    cntP  = (float*)(ws + OFF_CP);

        hipMemsetAsync(p2, 0, 3 * NCLS * sizeof(float), stream);
        prep_protos<<<dim3(96), dim3(64), 0, stream>>>(Ptf, Pde, Pff, W, p2);
        fusion_all<<<dim3(NRT), dim3(768), 0, stream>>>(
            Xtf, Xde, Xff, Vtf, Vde, Vff, W, p2, lossP, cntP);
        finalize2<<<dim3(1), dim3(256), 0, stream>>>(lossP, cntP, out);
    } else {
        hipMemsetAsync(out, 0, 2 * sizeof(float), stream);
        fusion_loss_fallback<<<dim3(NROWS / 16), dim3(NWAVES * 64), 0, stream>>>(
            Xtf, Ptf, Vtf, Xde, Pde, Vde, Xff, Pff, Vff, out);
    }
}